// Round 6
// baseline (171.160 us; speedup 1.0000x reference)
//
#include <hip/hip_runtime.h>
#include <hip/hip_cooperative_groups.h>
#include <cmath>

namespace cg = cooperative_groups;

typedef __bf16 bf16x8 __attribute__((ext_vector_type(8)));
typedef float f32x4 __attribute__((ext_vector_type(4)));

#define HEADS 16   // B*nH
#define TT 64      // T
#define FDIM 8192  // H*W*C
#define NCHUNK 32  // K-split chunks
#define CHUNKF 256 // FDIM / NCHUNK

// ================= Fused cooperative kernel: 512 blocks x 256 threads (2 blocks/CU) ======
// Phase A (all 512 blocks): part[chunk][h][p][q] = partial Q K^T   (R4 k1 verbatim)
// Phase B (128 thr/block):  Sbf[h][p][q] = bf16(sum_c part / 1024) (R4 k2, 128 elems/block)
// Phase C (all 512 blocks): out = gauss * S V, 256 cols/block (4x16-col tiles per wave)
__global__ __launch_bounds__(256, 2) void sdpa_fused2(const float* __restrict__ Q,
                                                      const float* __restrict__ Km,
                                                      const float* __restrict__ V,
                                                      float* __restrict__ out,
                                                      float* __restrict__ part,
                                                      __bf16* __restrict__ Sbf,
                                                      const float g_norm) {
    const int blk  = blockIdx.x;
    const int lane = threadIdx.x & 63;
    const int w    = threadIdx.x >> 6;
    const int r16  = lane & 15;
    const int g    = lane >> 4;

    // ---------------- Phase A ----------------
    {
        const int chunk = blk & (NCHUNK - 1);
        const int h     = blk >> 5;
        const int pr    = (w & 1) << 5;
        const int qr    = (w >> 1) << 5;
        const int kb    = chunk * CHUNKF + (g << 3);

        const float4* qp = (const float4*)(Q  + ((size_t)h * TT + pr + r16) * FDIM + kb);
        const float4* kp = (const float4*)(Km + ((size_t)h * TT + qr + r16) * FDIM + kb);

        f32x4 acc[2][2] = {{{0.f,0.f,0.f,0.f},{0.f,0.f,0.f,0.f}},
                           {{0.f,0.f,0.f,0.f},{0.f,0.f,0.f,0.f}}};

        #pragma unroll
        for (int ks = 0; ks < 8; ++ks) {
            bf16x8 a[2], bb[2];
            #pragma unroll
            for (int t = 0; t < 2; ++t) {
                const float4 x0 = qp[(size_t)t * 32768 + ks * 8];
                const float4 x1 = qp[(size_t)t * 32768 + ks * 8 + 1];
                a[t][0]=(__bf16)x0.x; a[t][1]=(__bf16)x0.y; a[t][2]=(__bf16)x0.z; a[t][3]=(__bf16)x0.w;
                a[t][4]=(__bf16)x1.x; a[t][5]=(__bf16)x1.y; a[t][6]=(__bf16)x1.z; a[t][7]=(__bf16)x1.w;
                const float4 y0 = kp[(size_t)t * 32768 + ks * 8];
                const float4 y1 = kp[(size_t)t * 32768 + ks * 8 + 1];
                bb[t][0]=(__bf16)y0.x; bb[t][1]=(__bf16)y0.y; bb[t][2]=(__bf16)y0.z; bb[t][3]=(__bf16)y0.w;
                bb[t][4]=(__bf16)y1.x; bb[t][5]=(__bf16)y1.y; bb[t][6]=(__bf16)y1.z; bb[t][7]=(__bf16)y1.w;
            }
            #pragma unroll
            for (int i = 0; i < 2; ++i)
                #pragma unroll
                for (int j = 0; j < 2; ++j)
                    acc[i][j] = __builtin_amdgcn_mfma_f32_16x16x32_bf16(a[i], bb[j], acc[i][j], 0, 0, 0);
        }

        float* pp = part + ((size_t)(blk & (NCHUNK - 1)) * HEADS + (blk >> 5)) * (TT * TT);
        #pragma unroll
        for (int i = 0; i < 2; ++i)
            #pragma unroll
            for (int j = 0; j < 2; ++j)
                #pragma unroll
                for (int r = 0; r < 4; ++r)
                    pp[(pr + (i << 4) + (g << 2) + r) * TT + (qr + (j << 4) + r16)] = acc[i][j][r];
    }

    cg::this_grid().sync();

    // ---------------- Phase B ----------------
    if (threadIdx.x < 128) {
        const int e = blk * 128 + threadIdx.x;   // 512*128 = 65536 = h*4096 + p*64 + q
        float s = 0.f;
        #pragma unroll
        for (int c = 0; c < NCHUNK; ++c)
            s += part[(size_t)c * (HEADS * TT * TT) + e];
        Sbf[e] = (__bf16)(s * (1.0f / 1024.0f));
    }

    cg::this_grid().sync();

    // ---------------- Phase C ----------------
    {
        const int h       = blk >> 5;           // 16 heads x 32 blocks
        const int colbase = (blk & 31) * 256 + w * 64;   // 64 cols per wave

        const __bf16* Sh = Sbf + h * (TT * TT);
        bf16x8 a[4][2];
        #pragma unroll
        for (int pt = 0; pt < 4; ++pt)
            #pragma unroll
            for (int ks = 0; ks < 2; ++ks)
                a[pt][ks] = *(const bf16x8*)(Sh + (pt * 16 + r16) * TT + ks * 32 + g * 8);

        const float* Vh = V + (size_t)h * TT * FDIM;
        f32x4 acc[4][4] = {};

        #pragma unroll
        for (int jt = 0; jt < 4; ++jt) {
            #pragma unroll
            for (int ks = 0; ks < 2; ++ks) {
                float vf[8];
                #pragma unroll
                for (int i = 0; i < 8; ++i)
                    vf[i] = Vh[(size_t)(ks * 32 + g * 8 + i) * FDIM + colbase + jt * 16 + r16];
                bf16x8 bb;
                #pragma unroll
                for (int i = 0; i < 8; ++i) bb[i] = (__bf16)vf[i];
                #pragma unroll
                for (int pt = 0; pt < 4; ++pt)
                    acc[pt][jt] = __builtin_amdgcn_mfma_f32_16x16x32_bf16(a[pt][ks], bb, acc[pt][jt], 0, 0, 0);
            }
        }

        #pragma unroll
        for (int jt = 0; jt < 4; ++jt) {
            const int col = colbase + jt * 16 + r16;
            const int m   = col >> 3;
            const float dx = (float)(m >> 5) - 15.5f;
            const float dy = (float)(m & 31) - 15.5f;
            const float gg = expf(-(dx * dx + dy * dy) * 0.02f) * g_norm;
            #pragma unroll
            for (int pt = 0; pt < 4; ++pt)
                #pragma unroll
                for (int r = 0; r < 4; ++r) {
                    const int p = pt * 16 + (g << 2) + r;
                    out[(size_t)h * TT * FDIM + (size_t)p * FDIM + col] = acc[pt][jt][r] * gg;
                }
        }
    }
}

// ================= Fallback path: proven R4 three-kernel pipeline (verbatim) =============
__global__ __launch_bounds__(256) void qk_partial(const float* __restrict__ Q,
                                                  const float* __restrict__ Km,
                                                  float* __restrict__ part) {
    const int chunk = blockIdx.x;
    const int h     = blockIdx.y;
    const int lane  = threadIdx.x & 63;
    const int w     = threadIdx.x >> 6;
    const int pr    = (w & 1) << 5;
    const int qr    = (w >> 1) << 5;
    const int r16   = lane & 15;
    const int g     = lane >> 4;
    const int kb    = chunk * CHUNKF + (g << 3);

    const float4* qp = (const float4*)(Q  + ((size_t)h * TT + pr + r16) * FDIM + kb);
    const float4* kp = (const float4*)(Km + ((size_t)h * TT + qr + r16) * FDIM + kb);

    f32x4 acc[2][2] = {{{0.f,0.f,0.f,0.f},{0.f,0.f,0.f,0.f}},
                       {{0.f,0.f,0.f,0.f},{0.f,0.f,0.f,0.f}}};

    #pragma unroll
    for (int ks = 0; ks < 8; ++ks) {
        bf16x8 a[2], b[2];
        #pragma unroll
        for (int t = 0; t < 2; ++t) {
            const float4 x0 = qp[(size_t)t * 32768 + ks * 8];
            const float4 x1 = qp[(size_t)t * 32768 + ks * 8 + 1];
            a[t][0]=(__bf16)x0.x; a[t][1]=(__bf16)x0.y; a[t][2]=(__bf16)x0.z; a[t][3]=(__bf16)x0.w;
            a[t][4]=(__bf16)x1.x; a[t][5]=(__bf16)x1.y; a[t][6]=(__bf16)x1.z; a[t][7]=(__bf16)x1.w;
            const float4 y0 = kp[(size_t)t * 32768 + ks * 8];
            const float4 y1 = kp[(size_t)t * 32768 + ks * 8 + 1];
            b[t][0]=(__bf16)y0.x; b[t][1]=(__bf16)y0.y; b[t][2]=(__bf16)y0.z; b[t][3]=(__bf16)y0.w;
            b[t][4]=(__bf16)y1.x; b[t][5]=(__bf16)y1.y; b[t][6]=(__bf16)y1.z; b[t][7]=(__bf16)y1.w;
        }
        #pragma unroll
        for (int i = 0; i < 2; ++i)
            #pragma unroll
            for (int j = 0; j < 2; ++j)
                acc[i][j] = __builtin_amdgcn_mfma_f32_16x16x32_bf16(a[i], b[j], acc[i][j], 0, 0, 0);
    }

    float* pp = part + ((size_t)chunk * HEADS + h) * (TT * TT);
    #pragma unroll
    for (int i = 0; i < 2; ++i)
        #pragma unroll
        for (int j = 0; j < 2; ++j)
            #pragma unroll
            for (int r = 0; r < 4; ++r)
                pp[(pr + (i << 4) + (g << 2) + r) * TT + (qr + (j << 4) + r16)] = acc[i][j][r];
}

__global__ __launch_bounds__(256) void reduce_sb(const float* __restrict__ part,
                                                 __bf16* __restrict__ Sbf) {
    const int e = blockIdx.x * 256 + threadIdx.x;
    float s = 0.f;
    #pragma unroll
    for (int c = 0; c < NCHUNK; ++c)
        s += part[(size_t)c * (HEADS * TT * TT) + e];
    Sbf[e] = (__bf16)(s * (1.0f / 1024.0f));
}

__global__ __launch_bounds__(256) void sv_mfma(const float* __restrict__ V,
                                               const __bf16* __restrict__ Sbf,
                                               float* __restrict__ out,
                                               const float g_norm) {
    const int h    = blockIdx.y;
    const int lane = threadIdx.x & 63;
    const int w    = threadIdx.x >> 6;
    const int r16  = lane & 15;
    const int g    = lane >> 4;
    const int colbase = blockIdx.x * 128 + w * 32;

    const __bf16* Sh = Sbf + h * (TT * TT);
    bf16x8 a[4][2];
    #pragma unroll
    for (int pt = 0; pt < 4; ++pt)
        #pragma unroll
        for (int ks = 0; ks < 2; ++ks)
            a[pt][ks] = *(const bf16x8*)(Sh + (pt * 16 + r16) * TT + ks * 32 + g * 8);

    const float* Vh = V + (size_t)h * TT * FDIM;
    f32x4 acc[4][2] = {};

    #pragma unroll
    for (int jt = 0; jt < 2; ++jt) {
        #pragma unroll
        for (int ks = 0; ks < 2; ++ks) {
            float vf[8];
            #pragma unroll
            for (int i = 0; i < 8; ++i)
                vf[i] = Vh[(size_t)(ks * 32 + g * 8 + i) * FDIM + colbase + jt * 16 + r16];
            bf16x8 b;
            #pragma unroll
            for (int i = 0; i < 8; ++i) b[i] = (__bf16)vf[i];
            #pragma unroll
            for (int pt = 0; pt < 4; ++pt)
                acc[pt][jt] = __builtin_amdgcn_mfma_f32_16x16x32_bf16(a[pt][ks], b, acc[pt][jt], 0, 0, 0);
        }
    }

    #pragma unroll
    for (int jt = 0; jt < 2; ++jt) {
        const int col = colbase + jt * 16 + r16;
        const int m   = col >> 3;
        const float dx = (float)(m >> 5) - 15.5f;
        const float dy = (float)(m & 31) - 15.5f;
        const float gg = expf(-(dx * dx + dy * dy) * 0.02f) * g_norm;
        #pragma unroll
        for (int pt = 0; pt < 4; ++pt)
            #pragma unroll
            for (int r = 0; r < 4; ++r) {
                const int p = pt * 16 + (g << 2) + r;
                out[(size_t)h * TT * FDIM + (size_t)p * FDIM + col] = acc[pt][jt][r] * gg;
            }
    }
}

extern "C" void kernel_launch(void* const* d_in, const int* in_sizes, int n_in,
                              void* d_out, int out_size, void* d_ws, size_t ws_size,
                              hipStream_t stream) {
    const float* Q  = (const float*)d_in[0];
    const float* Km = (const float*)d_in[1];
    const float* V  = (const float*)d_in[2];
    float* out  = (float*)d_out;
    float* part = (float*)d_out;     // 8.4 MB partials inside the 33.5 MB output buffer
    __bf16* Sbf = (__bf16*)d_ws;     // 128 KB bf16 S

    double sx = 0.0;
    for (int x = 0; x < 32; ++x) { const double d = (double)x - 15.5; sx += exp(-d * d / 50.0); }
    float g_norm = (float)(1.0 / (sx * sx));

    // --- Try fused cooperative path (512 blocks, 2/CU). Pure host query first; checked
    // launch with deterministic fallback to the proven 3-kernel pipeline on any failure.
    int nb = 0;
    hipError_t qe = hipOccupancyMaxActiveBlocksPerMultiprocessor(&nb, sdpa_fused2, 256, 0);
    if (qe == hipSuccess && nb >= 2) {
        void* args[] = {(void*)&Q, (void*)&Km, (void*)&V, (void*)&out,
                        (void*)&part, (void*)&Sbf, (void*)&g_norm};
        hipError_t le = hipLaunchCooperativeKernel((const void*)sdpa_fused2, dim3(512),
                                                   dim3(256), args, 0, stream);
        if (le == hipSuccess) return;
    }

    // --- Fallback: R4 pipeline ---
    qk_partial<<<dim3(NCHUNK, HEADS), 256, 0, stream>>>(Q, Km, part);
    reduce_sb<<<dim3((HEADS * TT * TT) / 256), 256, 0, stream>>>(part, Sbf);
    sv_mfma<<<dim3(FDIM / 128, HEADS), 256, 0, stream>>>(V, Sbf, out, g_norm);
}

// Round 7
// 44.811 us; speedup vs baseline: 3.8196x; 3.8196x over previous
//
#include <hip/hip_runtime.h>
#include <cmath>

typedef __bf16 bf16x8 __attribute__((ext_vector_type(8)));
typedef float f32x4 __attribute__((ext_vector_type(4)));

#define HEADS 16   // B*nH
#define TT 64      // T
#define FDIM 8192  // H*W*C
#define NCHUNK 32  // K-split chunks
#define CHUNKF 256 // FDIM / NCHUNK

// ---------------- Kernel 0: zero the 256KB fp32 S accumulator ----------------
__global__ __launch_bounds__(256) void zero_s(float4* __restrict__ Sf4) {
    Sf4[blockIdx.x * 256 + threadIdx.x] = (float4){0.f, 0.f, 0.f, 0.f};
}

// ---------------- Kernel 1: S[h][p][q] += partial Q K^T (bf16 MFMA + atomics) -----------
// grid (NCHUNK, HEADS), block 256 (4 waves, 2x2 wave tiling). Same proven MFMA body as R4;
// the fp32 partial round-trip (8.4MB write + 8.4MB read) is replaced by atomicAdd into a
// 256KB L2-resident S buffer. Scale 1/1024 deferred to k3's epilogue (exactly linear).
__global__ __launch_bounds__(256) void qk_atomic(const float* __restrict__ Q,
                                                 const float* __restrict__ Km,
                                                 float* __restrict__ Sf) {
    const int chunk = blockIdx.x;
    const int h     = blockIdx.y;
    const int lane  = threadIdx.x & 63;
    const int w     = threadIdx.x >> 6;
    const int pr    = (w & 1) << 5;
    const int qr    = (w >> 1) << 5;
    const int r16   = lane & 15;
    const int g     = lane >> 4;
    const int kb    = chunk * CHUNKF + (g << 3);

    const float4* qp = (const float4*)(Q  + ((size_t)h * TT + pr + r16) * FDIM + kb);
    const float4* kp = (const float4*)(Km + ((size_t)h * TT + qr + r16) * FDIM + kb);

    f32x4 acc[2][2] = {{{0.f,0.f,0.f,0.f},{0.f,0.f,0.f,0.f}},
                       {{0.f,0.f,0.f,0.f},{0.f,0.f,0.f,0.f}}};

    #pragma unroll
    for (int ks = 0; ks < 8; ++ks) {
        bf16x8 a[2], b[2];
        #pragma unroll
        for (int t = 0; t < 2; ++t) {
            const float4 x0 = qp[(size_t)t * 32768 + ks * 8];
            const float4 x1 = qp[(size_t)t * 32768 + ks * 8 + 1];
            a[t][0]=(__bf16)x0.x; a[t][1]=(__bf16)x0.y; a[t][2]=(__bf16)x0.z; a[t][3]=(__bf16)x0.w;
            a[t][4]=(__bf16)x1.x; a[t][5]=(__bf16)x1.y; a[t][6]=(__bf16)x1.z; a[t][7]=(__bf16)x1.w;
            const float4 y0 = kp[(size_t)t * 32768 + ks * 8];
            const float4 y1 = kp[(size_t)t * 32768 + ks * 8 + 1];
            b[t][0]=(__bf16)y0.x; b[t][1]=(__bf16)y0.y; b[t][2]=(__bf16)y0.z; b[t][3]=(__bf16)y0.w;
            b[t][4]=(__bf16)y1.x; b[t][5]=(__bf16)y1.y; b[t][6]=(__bf16)y1.z; b[t][7]=(__bf16)y1.w;
        }
        #pragma unroll
        for (int i = 0; i < 2; ++i)
            #pragma unroll
            for (int j = 0; j < 2; ++j)
                acc[i][j] = __builtin_amdgcn_mfma_f32_16x16x32_bf16(a[i], b[j], acc[i][j], 0, 0, 0);
    }

    // Accumulate into S[h][p][q] (fp32, 256KB total -> L2-resident; each address hit 32x).
    float* Sh = Sf + h * (TT * TT);
    #pragma unroll
    for (int i = 0; i < 2; ++i)
        #pragma unroll
        for (int j = 0; j < 2; ++j)
            #pragma unroll
            for (int r = 0; r < 4; ++r)
                atomicAdd(&Sh[(pr + (i << 4) + (g << 2) + r) * TT + (qr + (j << 4) + r16)],
                          acc[i][j][r]);
}

// ---------------- Kernel 3: O[h][p][j] = gauss[j>>3]/1024 * sum_q S[h][p][q] * V[h][q][j]
// MFMA (proven R4 body); A-fragments now read fp32 S (L2-resident) and convert in-register.
__global__ __launch_bounds__(256) void sv_mfma(const float* __restrict__ V,
                                               const float* __restrict__ Sf,
                                               float* __restrict__ out,
                                               const float g_scale) {
    const int h    = blockIdx.y;
    const int lane = threadIdx.x & 63;
    const int w    = threadIdx.x >> 6;
    const int r16  = lane & 15;
    const int g    = lane >> 4;
    const int colbase = blockIdx.x * 128 + w * 32;

    // A-fragments: a[pt][ks] = bf16(S[pt*16 + r16][ks*32 + g*8 .. +8])
    const float* Sh = Sf + h * (TT * TT);
    bf16x8 a[4][2];
    #pragma unroll
    for (int pt = 0; pt < 4; ++pt)
        #pragma unroll
        for (int ks = 0; ks < 2; ++ks) {
            const float4 s0 = *(const float4*)(Sh + (pt * 16 + r16) * TT + ks * 32 + g * 8);
            const float4 s1 = *(const float4*)(Sh + (pt * 16 + r16) * TT + ks * 32 + g * 8 + 4);
            a[pt][ks][0]=(__bf16)s0.x; a[pt][ks][1]=(__bf16)s0.y;
            a[pt][ks][2]=(__bf16)s0.z; a[pt][ks][3]=(__bf16)s0.w;
            a[pt][ks][4]=(__bf16)s1.x; a[pt][ks][5]=(__bf16)s1.y;
            a[pt][ks][6]=(__bf16)s1.z; a[pt][ks][7]=(__bf16)s1.w;
        }

    const float* Vh = V + (size_t)h * TT * FDIM;
    f32x4 acc[4][2] = {};

    #pragma unroll
    for (int jt = 0; jt < 2; ++jt) {
        #pragma unroll
        for (int ks = 0; ks < 2; ++ks) {
            float vf[8];
            #pragma unroll
            for (int i = 0; i < 8; ++i)
                vf[i] = Vh[(size_t)(ks * 32 + g * 8 + i) * FDIM + colbase + jt * 16 + r16];
            bf16x8 b;
            #pragma unroll
            for (int i = 0; i < 8; ++i) b[i] = (__bf16)vf[i];
            #pragma unroll
            for (int pt = 0; pt < 4; ++pt)
                acc[pt][jt] = __builtin_amdgcn_mfma_f32_16x16x32_bf16(a[pt][ks], b, acc[pt][jt], 0, 0, 0);
        }
    }

    // Epilogue: gaussian column weight * (1/1024) [folded into g_scale], store.
    #pragma unroll
    for (int jt = 0; jt < 2; ++jt) {
        const int col = colbase + jt * 16 + r16;
        const int m   = col >> 3;
        const float dx = (float)(m >> 5) - 15.5f;
        const float dy = (float)(m & 31) - 15.5f;
        const float gg = expf(-(dx * dx + dy * dy) * 0.02f) * g_scale;
        #pragma unroll
        for (int pt = 0; pt < 4; ++pt)
            #pragma unroll
            for (int r = 0; r < 4; ++r) {
                const int p = pt * 16 + (g << 2) + r;
                out[(size_t)h * TT * FDIM + (size_t)p * FDIM + col] = acc[pt][jt][r] * gg;
            }
    }
}

extern "C" void kernel_launch(void* const* d_in, const int* in_sizes, int n_in,
                              void* d_out, int out_size, void* d_ws, size_t ws_size,
                              hipStream_t stream) {
    const float* Q  = (const float*)d_in[0];
    const float* Km = (const float*)d_in[1];
    const float* V  = (const float*)d_in[2];
    float* out = (float*)d_out;
    float* Sf  = (float*)d_ws;     // 256 KB fp32 S accumulator (zeroed per call)

    // Host-side: separable Gaussian normalizer * 1/1024 scale (exact, deterministic).
    double sx = 0.0;
    for (int x = 0; x < 32; ++x) { const double d = (double)x - 15.5; sx += exp(-d * d / 50.0); }
    const float g_scale = (float)(1.0 / (sx * sx) / 1024.0);

    zero_s<<<dim3((HEADS * TT * TT) / 1024), 256, 0, stream>>>((float4*)Sf);
    qk_atomic<<<dim3(NCHUNK, HEADS), 256, 0, stream>>>(Q, Km, Sf);
    sv_mfma<<<dim3(FDIM / 128, HEADS), 256, 0, stream>>>(V, Sf, out, g_scale);
}

// Round 8
// 37.546 us; speedup vs baseline: 4.5586x; 1.1935x over previous
//
#include <hip/hip_runtime.h>
#include <cmath>

typedef __bf16 bf16x8 __attribute__((ext_vector_type(8)));
typedef float f32x4 __attribute__((ext_vector_type(4)));

#define HEADS 16   // B*nH
#define TT 64      // T
#define FDIM 8192  // H*W*C
#define NCHUNK 32  // K-split chunks
#define CHUNKF 256 // FDIM / NCHUNK

// ---------------- Kernel 1: partial S = Q K^T over one f-chunk (bf16 MFMA) --------------
// grid (NCHUNK, HEADS), block 256 (4 waves, 2x2 wave tiling). R4 body; partials now bf16
// (halves the partial round-trip: 8.4 MB -> 4.2 MB each way).
__global__ __launch_bounds__(256) void qk_partial(const float* __restrict__ Q,
                                                  const float* __restrict__ Km,
                                                  __bf16* __restrict__ part) {
    const int chunk = blockIdx.x;
    const int h     = blockIdx.y;
    const int lane  = threadIdx.x & 63;
    const int w     = threadIdx.x >> 6;
    const int pr    = (w & 1) << 5;
    const int qr    = (w >> 1) << 5;
    const int r16   = lane & 15;
    const int g     = lane >> 4;
    const int kb    = chunk * CHUNKF + (g << 3);

    const float4* qp = (const float4*)(Q  + ((size_t)h * TT + pr + r16) * FDIM + kb);
    const float4* kp = (const float4*)(Km + ((size_t)h * TT + qr + r16) * FDIM + kb);

    f32x4 acc[2][2] = {{{0.f,0.f,0.f,0.f},{0.f,0.f,0.f,0.f}},
                       {{0.f,0.f,0.f,0.f},{0.f,0.f,0.f,0.f}}};

    #pragma unroll
    for (int ks = 0; ks < 8; ++ks) {
        bf16x8 a[2], b[2];
        #pragma unroll
        for (int t = 0; t < 2; ++t) {
            const float4 x0 = qp[(size_t)t * 32768 + ks * 8];
            const float4 x1 = qp[(size_t)t * 32768 + ks * 8 + 1];
            a[t][0]=(__bf16)x0.x; a[t][1]=(__bf16)x0.y; a[t][2]=(__bf16)x0.z; a[t][3]=(__bf16)x0.w;
            a[t][4]=(__bf16)x1.x; a[t][5]=(__bf16)x1.y; a[t][6]=(__bf16)x1.z; a[t][7]=(__bf16)x1.w;
            const float4 y0 = kp[(size_t)t * 32768 + ks * 8];
            const float4 y1 = kp[(size_t)t * 32768 + ks * 8 + 1];
            b[t][0]=(__bf16)y0.x; b[t][1]=(__bf16)y0.y; b[t][2]=(__bf16)y0.z; b[t][3]=(__bf16)y0.w;
            b[t][4]=(__bf16)y1.x; b[t][5]=(__bf16)y1.y; b[t][6]=(__bf16)y1.z; b[t][7]=(__bf16)y1.w;
        }
        #pragma unroll
        for (int i = 0; i < 2; ++i)
            #pragma unroll
            for (int j = 0; j < 2; ++j)
                acc[i][j] = __builtin_amdgcn_mfma_f32_16x16x32_bf16(a[i], b[j], acc[i][j], 0, 0, 0);
    }

    // part[chunk][h][p][q] in bf16
    __bf16* pp = part + ((size_t)chunk * HEADS + h) * (TT * TT);
    #pragma unroll
    for (int i = 0; i < 2; ++i)
        #pragma unroll
        for (int j = 0; j < 2; ++j)
            #pragma unroll
            for (int r = 0; r < 4; ++r)
                pp[(pr + (i << 4) + (g << 2) + r) * TT + (qr + (j << 4) + r16)] =
                    (__bf16)acc[i][j][r];
}

// ---------------- Kernel 2: reduce bf16 partials over chunks, scale, emit bf16 S --------
// Each thread handles one dword = 2 adjacent bf16 elements. 32768 pairs -> 128 blocks.
__global__ __launch_bounds__(256) void reduce_sb(const unsigned int* __restrict__ partU,
                                                 __bf16* __restrict__ Sbf) {
    const int e = blockIdx.x * 256 + threadIdx.x;   // pair index, 32768 total
    float s0 = 0.f, s1 = 0.f;
    #pragma unroll
    for (int c = 0; c < NCHUNK; ++c) {
        const unsigned int u = partU[(size_t)c * 32768 + e];
        s0 += __uint_as_float(u << 16);            // low bf16 -> f32
        s1 += __uint_as_float(u & 0xffff0000u);    // high bf16 -> f32
    }
    Sbf[2 * e]     = (__bf16)(s0 * (1.0f / 1024.0f));
    Sbf[2 * e + 1] = (__bf16)(s1 * (1.0f / 1024.0f));
}

// ---------------- Kernel 3: O[h][p][j] = gauss[j>>3] * sum_q S[h][p][q] * V[h][q][j] -----
// MFMA (proven R4 body) + non-temporal output stores (out is never re-read; keep L2/L3
// for the replay-resident V/Q/K instead).
__global__ __launch_bounds__(256) void sv_mfma(const float* __restrict__ V,
                                               const __bf16* __restrict__ Sbf,
                                               float* __restrict__ out,
                                               const float g_norm) {
    const int h    = blockIdx.y;
    const int lane = threadIdx.x & 63;
    const int w    = threadIdx.x >> 6;
    const int r16  = lane & 15;
    const int g    = lane >> 4;
    const int colbase = blockIdx.x * 128 + w * 32;

    const __bf16* Sh = Sbf + h * (TT * TT);
    bf16x8 a[4][2];
    #pragma unroll
    for (int pt = 0; pt < 4; ++pt)
        #pragma unroll
        for (int ks = 0; ks < 2; ++ks)
            a[pt][ks] = *(const bf16x8*)(Sh + (pt * 16 + r16) * TT + ks * 32 + g * 8);

    const float* Vh = V + (size_t)h * TT * FDIM;
    f32x4 acc[4][2] = {};

    #pragma unroll
    for (int jt = 0; jt < 2; ++jt) {
        #pragma unroll
        for (int ks = 0; ks < 2; ++ks) {
            float vf[8];
            #pragma unroll
            for (int i = 0; i < 8; ++i)
                vf[i] = Vh[(size_t)(ks * 32 + g * 8 + i) * FDIM + colbase + jt * 16 + r16];
            bf16x8 b;
            #pragma unroll
            for (int i = 0; i < 8; ++i) b[i] = (__bf16)vf[i];
            #pragma unroll
            for (int pt = 0; pt < 4; ++pt)
                acc[pt][jt] = __builtin_amdgcn_mfma_f32_16x16x32_bf16(a[pt][ks], b, acc[pt][jt], 0, 0, 0);
        }
    }

    #pragma unroll
    for (int jt = 0; jt < 2; ++jt) {
        const int col = colbase + jt * 16 + r16;
        const int m   = col >> 3;
        const float dx = (float)(m >> 5) - 15.5f;
        const float dy = (float)(m & 31) - 15.5f;
        const float gg = expf(-(dx * dx + dy * dy) * 0.02f) * g_norm;
        #pragma unroll
        for (int pt = 0; pt < 4; ++pt)
            #pragma unroll
            for (int r = 0; r < 4; ++r) {
                const int p = pt * 16 + (g << 2) + r;
                __builtin_nontemporal_store(acc[pt][jt][r] * gg,
                    &out[(size_t)h * TT * FDIM + (size_t)p * FDIM + col]);
            }
    }
}

extern "C" void kernel_launch(void* const* d_in, const int* in_sizes, int n_in,
                              void* d_out, int out_size, void* d_ws, size_t ws_size,
                              hipStream_t stream) {
    const float* Q  = (const float*)d_in[0];
    const float* Km = (const float*)d_in[1];
    const float* V  = (const float*)d_in[2];
    float* out = (float*)d_out;
    // ws layout: [0, 128KB) bf16 S; partials (4.2 MB bf16) live inside d_out's first half
    // (d_out is 33.5 MB; partials are dead before k3 overwrites any of it).
    __bf16* Sbf  = (__bf16*)d_ws;
    __bf16* part = (__bf16*)d_out;

    // Host-side separable Gaussian normalizer (exact, deterministic):
    double sx = 0.0;
    for (int x = 0; x < 32; ++x) { const double d = (double)x - 15.5; sx += exp(-d * d / 50.0); }
    const float g_norm = (float)(1.0 / (sx * sx));

    qk_partial<<<dim3(NCHUNK, HEADS), 256, 0, stream>>>(Q, Km, part);
    reduce_sb<<<dim3(128), 256, 0, stream>>>((const unsigned int*)part, Sbf);
    sv_mfma<<<dim3(FDIM / 128, HEADS), 256, 0, stream>>>(V, Sbf, out, g_norm);
}